// Round 2
// baseline (386.930 us; speedup 1.0000x reference)
//
#include <hip/hip_runtime.h>
#include <hip/hip_bf16.h>
#include <stdint.h>

typedef __bf16 bf16x8 __attribute__((ext_vector_type(8)));
typedef float f32x4 __attribute__((ext_vector_type(4)));
typedef float f32x4v __attribute__((ext_vector_type(4)));
typedef unsigned short u16;
typedef unsigned int u32;
typedef u16 u16x8 __attribute__((ext_vector_type(8)));

#define B_ 2
#define S_ 2048
#define HID_ 2048
#define H_ 16
#define HK_ 4
#define D_ 128
#define NQKV_ 3072

__device__ __forceinline__ u16 f2bf(float f) {
  u32 u = __builtin_bit_cast(u32, f);
  u32 r = (u + 0x7fffu + ((u >> 16) & 1u)) >> 16;
  return (u16)r;
}

__device__ __forceinline__ void gload_lds16(const void* g, void* l) {
  __builtin_amdgcn_global_load_lds((const __attribute__((address_space(1))) void*)g,
                                   (__attribute__((address_space(3))) void*)l, 16, 0, 0);
}

// ---------------- f32 -> bf16 bulk convert ----------------
__global__ __launch_bounds__(256) void k_f32_to_bf16(const float* __restrict__ in,
                                                     u16* __restrict__ out, int n8) {
  for (int i = blockIdx.x * 256 + threadIdx.x; i < n8; i += gridDim.x * 256) {
    const f32x4v* p = (const f32x4v*)(in + (size_t)i * 8);
    f32x4v a = p[0], b = p[1];
    u16x8 w;
    w[0] = f2bf(a[0]); w[1] = f2bf(a[1]); w[2] = f2bf(a[2]); w[3] = f2bf(a[3]);
    w[4] = f2bf(b[0]); w[5] = f2bf(b[1]); w[6] = f2bf(b[2]); w[7] = f2bf(b[3]);
    *(u16x8*)(out + (size_t)i * 8) = w;
  }
}

// ---------------- bf16 GEMM: C[M][N] = A[M][K] * B[N][K]^T + bias ----------------
__global__ __launch_bounds__(256) void k_gemm_bt(const u16* __restrict__ A, const u16* __restrict__ Bm,
                                                 const float* __restrict__ bias, float* __restrict__ C,
                                                 int M, int N, int K) {
  __shared__ __attribute__((aligned(16))) u16 lA[128 * 32];
  __shared__ __attribute__((aligned(16))) u16 lB[128 * 32];
  const int tid = threadIdx.x;
  const int lane = tid & 63, wid = tid >> 6;
  const int wr = wid >> 1, wc = wid & 1;
  const int row0 = blockIdx.y * 128, col0 = blockIdx.x * 128;
  const int l15 = lane & 15, l4 = lane >> 4;
  f32x4 acc[4][4] = {};

  for (int k0 = 0; k0 < K; k0 += 32) {
#pragma unroll
    for (int iss = 0; iss < 2; ++iss) {
      int ob_w = wid * 2048 + iss * 1024;   // wave-uniform LDS byte base
      int ob = ob_w + lane * 16;            // this lane's byte offset within tile
      int r = ob >> 6, cb = ob & 63;
      gload_lds16((const char*)A + ((size_t)(row0 + r) * K + k0) * 2 + cb, (char*)lA + ob_w);
      gload_lds16((const char*)Bm + ((size_t)(col0 + r) * K + k0) * 2 + cb, (char*)lB + ob_w);
    }
    __syncthreads();
    bf16x8 af[4], bf[4];
#pragma unroll
    for (int m = 0; m < 4; ++m) af[m] = *(const bf16x8*)&lA[(wr * 64 + m * 16 + l15) * 32 + l4 * 8];
#pragma unroll
    for (int n = 0; n < 4; ++n) bf[n] = *(const bf16x8*)&lB[(wc * 64 + n * 16 + l15) * 32 + l4 * 8];
#pragma unroll
    for (int m = 0; m < 4; ++m)
#pragma unroll
      for (int n = 0; n < 4; ++n)
        acc[m][n] = __builtin_amdgcn_mfma_f32_16x16x32_bf16(af[m], bf[n], acc[m][n], 0, 0, 0);
    __syncthreads();
  }
#pragma unroll
  for (int m = 0; m < 4; ++m) {
    int grow_b = row0 + wr * 64 + m * 16 + l4 * 4;
#pragma unroll
    for (int n = 0; n < 4; ++n) {
      int gcol = col0 + wc * 64 + n * 16 + l15;
      float bv = bias[gcol];
#pragma unroll
      for (int r2 = 0; r2 < 4; ++r2)
        C[(size_t)(grow_b + r2) * N + gcol] = acc[m][n][r2] + bv;
    }
  }
}

// ---------------- RoPE + split + layout ----------------
__global__ __launch_bounds__(256) void k_rope_split(const float* __restrict__ qkv,
                                                    const float* __restrict__ cosb,
                                                    const float* __restrict__ sinb,
                                                    u16* __restrict__ Qb, u16* __restrict__ Kb,
                                                    u16* __restrict__ Vt) {
  const int bs = blockIdx.x;
  const int b = bs >> 11, s = bs & 2047;
  const size_t base = (size_t)bs * NQKV_;
  const size_t cs = (size_t)bs * D_;
  const float qscale = 0.08838834764831845f;  // 1/sqrt(128)
  for (int p = threadIdx.x; p < H_ * 64; p += 256) {
    int h = p >> 6, d = p & 63;
    float f1 = qkv[base + h * D_ + d];
    float f2 = qkv[base + h * D_ + 64 + d];
    float c1 = cosb[cs + d], s1 = sinb[cs + d];
    float c2 = cosb[cs + 64 + d], s2 = sinb[cs + 64 + d];
    size_t o = ((size_t)(b * H_ + h) * S_ + s) * D_ + d;
    Qb[o] = f2bf((f1 * c1 - f2 * s1) * qscale);
    Qb[o + 64] = f2bf((f2 * c2 + f1 * s2) * qscale);
  }
  for (int p = threadIdx.x; p < HK_ * 64; p += 256) {
    int hk = p >> 6, d = p & 63;
    float f1 = qkv[base + H_ * D_ + hk * D_ + d];
    float f2 = qkv[base + H_ * D_ + hk * D_ + 64 + d];
    float c1 = cosb[cs + d], s1 = sinb[cs + d];
    float c2 = cosb[cs + 64 + d], s2 = sinb[cs + 64 + d];
    size_t o = ((size_t)(b * HK_ + hk) * S_ + s) * D_ + d;
    Kb[o] = f2bf(f1 * c1 - f2 * s1);
    Kb[o + 64] = f2bf(f2 * c2 + f1 * s2);
  }
  for (int p = threadIdx.x; p < HK_ * D_; p += 256) {
    int hk = p >> 7, d = p & 127;
    float v = qkv[base + H_ * D_ + HK_ * D_ + hk * D_ + d];
    Vt[((size_t)(b * HK_ + hk) * D_ + d) * S_ + s] = f2bf(v);
  }
}

// ---------------- flash attention: 128 q-rows/block, 4 waves x 32 rows ----------------
__global__ __launch_bounds__(256) void k_attn(const u16* __restrict__ Qb, const u16* __restrict__ Kb,
                                              const u16* __restrict__ Vt, u16* __restrict__ Ob) {
  __shared__ __attribute__((aligned(16))) u16 lK[64 * 128];   // [key][d], XOR-swizzled
  __shared__ __attribute__((aligned(16))) u16 lV[128 * 64];   // [d][key], XOR-swizzled
  __shared__ __attribute__((aligned(16))) u16 lP[4][32 * 72]; // per-wave P (32 rows), padded
  const int qt = blockIdx.x;   // 0..15
  const int bh = blockIdx.y;   // 0..31
  const int b = bh >> 4, h = bh & 15;
  const int hk = h >> 2;
  const int tid = threadIdx.x, lane = tid & 63, wid = tid >> 6;
  const int l15 = lane & 15, l4 = lane >> 4;

  const int qrow0 = qt * 128 + wid * 32;
  const u16* qb = Qb + ((size_t)(b * H_ + h) * S_ + qrow0 + l15) * D_;
  bf16x8 qf[2][4];
#pragma unroll
  for (int m = 0; m < 2; ++m)
#pragma unroll
    for (int ks = 0; ks < 4; ++ks)
      qf[m][ks] = *(const bf16x8*)(qb + (size_t)m * 16 * D_ + ks * 32 + l4 * 8);

  const u16* kbase = Kb + (size_t)(b * HK_ + hk) * S_ * D_;
  const u16* vbase = Vt + (size_t)(b * HK_ + hk) * D_ * S_;

  f32x4 o[2][8] = {};
  float mrun[2][4], lrun[2][4];
#pragma unroll
  for (int m = 0; m < 2; ++m)
#pragma unroll
    for (int r = 0; r < 4; ++r) { mrun[m][r] = -1e30f; lrun[m][r] = 0.f; }

  char* lKc = (char*)lK;
  char* lVc = (char*)lV;
  u16* myP = &lP[wid][0];

  bf16x8 kreg[4], vreg[4];
  // addressing for staging: 4 iters x 256 threads
  int kr_[4], c16_[4], vr_[4], c8_[4];
#pragma unroll
  for (int it = 0; it < 4; ++it) {
    int idx = it * 256 + tid;
    kr_[it] = idx >> 4; c16_[it] = idx & 15;
    vr_[it] = idx >> 3; c8_[it] = idx & 7;
  }

  // prologue: stage kt=0
#pragma unroll
  for (int it = 0; it < 4; ++it) {
    kreg[it] = *(const bf16x8*)(kbase + (size_t)kr_[it] * D_ + c16_[it] * 8);
    vreg[it] = *(const bf16x8*)(vbase + (size_t)vr_[it] * S_ + c8_[it] * 8);
  }
#pragma unroll
  for (int it = 0; it < 4; ++it) {
    *(bf16x8*)(lKc + ((kr_[it] * 256 + c16_[it] * 16) ^ ((kr_[it] & 7) << 4))) = kreg[it];
    *(bf16x8*)(lVc + ((vr_[it] * 128 + c8_[it] * 16) ^ ((vr_[it] & 7) << 4))) = vreg[it];
  }
  __syncthreads();

  for (int kt = 0; kt < 32; ++kt) {
    // async-stage: issue next tile's global loads now, consume after the barrier
    if (kt < 31) {
#pragma unroll
      for (int it = 0; it < 4; ++it) {
        kreg[it] = *(const bf16x8*)(kbase + (size_t)((kt + 1) * 64 + kr_[it]) * D_ + c16_[it] * 8);
        vreg[it] = *(const bf16x8*)(vbase + (size_t)vr_[it] * S_ + (kt + 1) * 64 + c8_[it] * 8);
      }
    }

    // scores: S[32 x 64] = Q(32x128) . K_tile^T
    f32x4 sc[2][4] = {};
    __builtin_amdgcn_s_setprio(1);
#pragma unroll
    for (int ks = 0; ks < 4; ++ks) {
#pragma unroll
      for (int nf = 0; nf < 4; ++nf) {
        int kr = nf * 16 + l15;
        bf16x8 kf = *(const bf16x8*)(lKc + ((kr * 256 + ks * 64 + l4 * 16) ^ ((kr & 7) << 4)));
        sc[0][nf] = __builtin_amdgcn_mfma_f32_16x16x32_bf16(qf[0][ks], kf, sc[0][nf], 0, 0, 0);
        sc[1][nf] = __builtin_amdgcn_mfma_f32_16x16x32_bf16(qf[1][ks], kf, sc[1][nf], 0, 0, 0);
      }
    }
    __builtin_amdgcn_s_setprio(0);

    // online softmax per row-frag
#pragma unroll
    for (int m = 0; m < 2; ++m) {
      float alpha[4];
#pragma unroll
      for (int r = 0; r < 4; ++r) {
        float mx = fmaxf(fmaxf(sc[m][0][r], sc[m][1][r]), fmaxf(sc[m][2][r], sc[m][3][r]));
#pragma unroll
        for (int sh = 1; sh < 16; sh <<= 1) mx = fmaxf(mx, __shfl_xor(mx, sh));
        float mn = fmaxf(mrun[m][r], mx);
        alpha[r] = __expf(mrun[m][r] - mn);
        mrun[m][r] = mn;
        float rs = 0.f;
#pragma unroll
        for (int nf = 0; nf < 4; ++nf) {
          float p = __expf(sc[m][nf][r] - mn);
          sc[m][nf][r] = p;
          rs += p;
        }
#pragma unroll
        for (int sh = 1; sh < 16; sh <<= 1) rs += __shfl_xor(rs, sh);
        lrun[m][r] = lrun[m][r] * alpha[r] + rs;
      }
#pragma unroll
      for (int nf2 = 0; nf2 < 8; ++nf2)
#pragma unroll
        for (int r = 0; r < 4; ++r) o[m][nf2][r] *= alpha[r];

      // P -> LDS (C-layout write), rows m*16 + l4*4 + r, padded row = 72 u16
#pragma unroll
      for (int r = 0; r < 4; ++r) {
        int prow = m * 16 + l4 * 4 + r;
#pragma unroll
        for (int nf = 0; nf < 4; ++nf)
          myP[prow * 72 + nf * 16 + l15] = f2bf(sc[m][nf][r]);
      }
    }

    // PV: O[m] += P[m](16x64) . V_tile(64x128), V-frags shared across m
    __builtin_amdgcn_s_setprio(1);
#pragma unroll
    for (int ks2 = 0; ks2 < 2; ++ks2) {
      bf16x8 pf0 = *(const bf16x8*)((char*)myP + (0 * 16 + l15) * 144 + ks2 * 64 + l4 * 16);
      bf16x8 pf1 = *(const bf16x8*)((char*)myP + (1 * 16 + l15) * 144 + ks2 * 64 + l4 * 16);
#pragma unroll
      for (int nf2 = 0; nf2 < 8; ++nf2) {
        int dr = nf2 * 16 + l15;
        bf16x8 vf = *(const bf16x8*)(lVc + ((dr * 128 + ks2 * 64 + l4 * 16) ^ ((dr & 7) << 4)));
        o[0][nf2] = __builtin_amdgcn_mfma_f32_16x16x32_bf16(pf0, vf, o[0][nf2], 0, 0, 0);
        o[1][nf2] = __builtin_amdgcn_mfma_f32_16x16x32_bf16(pf1, vf, o[1][nf2], 0, 0, 0);
      }
    }
    __builtin_amdgcn_s_setprio(0);

    __syncthreads();
    if (kt < 31) {
#pragma unroll
      for (int it = 0; it < 4; ++it) {
        *(bf16x8*)(lKc + ((kr_[it] * 256 + c16_[it] * 16) ^ ((kr_[it] & 7) << 4))) = kreg[it];
        *(bf16x8*)(lVc + ((vr_[it] * 128 + c8_[it] * 16) ^ ((vr_[it] & 7) << 4))) = vreg[it];
      }
    }
    __syncthreads();
  }

  // epilogue: attn_out [b][s][h*D+d] bf16
#pragma unroll
  for (int m = 0; m < 2; ++m)
#pragma unroll
    for (int r = 0; r < 4; ++r) {
      int s = qt * 128 + wid * 32 + m * 16 + l4 * 4 + r;
      float inv = 1.0f / lrun[m][r];
      size_t ob = ((size_t)(b * S_ + s)) * HID_ + h * D_;
#pragma unroll
      for (int nf2 = 0; nf2 < 8; ++nf2)
        Ob[ob + nf2 * 16 + l15] = f2bf(o[m][nf2][r] * inv);
    }
}

extern "C" void kernel_launch(void* const* d_in, const int* in_sizes, int n_in,
                              void* d_out, int out_size, void* d_ws, size_t ws_size,
                              hipStream_t stream) {
  const float* hs = (const float*)d_in[0];
  const float* cosb = (const float*)d_in[1];
  const float* sinb = (const float*)d_in[2];
  const float* w_qkv = (const float*)d_in[3];
  const float* b_qkv = (const float*)d_in[4];
  const float* w_o = (const float*)d_in[5];
  const float* b_o = (const float*)d_in[6];
  float* out = (float*)d_out;

  char* ws = (char*)d_ws;
  u16* Xb    = (u16*)ws;                          // 16,777,216 B (reused as attn_out)
  u16* Wqkvb = (u16*)(ws + 16777216);             // 12,582,912 B
  u16* Wob   = (u16*)(ws + 29360128);             //  8,388,608 B
  float* qkv = (float*)(ws + 37748736);           // 50,331,648 B
  u16* Qb    = (u16*)(ws + 88080384);             // 16,777,216 B
  u16* Kb    = (u16*)(ws + 104857600);            //  4,194,304 B
  u16* Vt    = (u16*)(ws + 109051904);            //  4,194,304 B  (total 113,246,208 B)
  u16* Ob = Xb;

  hipLaunchKernelGGL(k_f32_to_bf16, dim3(2048), dim3(256), 0, stream, hs, Xb, (B_ * S_ * HID_) / 8);
  hipLaunchKernelGGL(k_f32_to_bf16, dim3(1536), dim3(256), 0, stream, w_qkv, Wqkvb, (NQKV_ * HID_) / 8);
  hipLaunchKernelGGL(k_f32_to_bf16, dim3(1024), dim3(256), 0, stream, w_o, Wob, (HID_ * HID_) / 8);
  hipLaunchKernelGGL(k_gemm_bt, dim3(NQKV_ / 128, (B_ * S_) / 128), dim3(256), 0, stream,
                     Xb, Wqkvb, b_qkv, qkv, B_ * S_, NQKV_, HID_);
  hipLaunchKernelGGL(k_rope_split, dim3(B_ * S_), dim3(256), 0, stream, qkv, cosb, sinb, Qb, Kb, Vt);
  hipLaunchKernelGGL(k_attn, dim3(S_ / 128, B_ * H_), dim3(256), 0, stream, Qb, Kb, Vt, Ob);
  hipLaunchKernelGGL(k_gemm_bt, dim3(HID_ / 128, (B_ * S_) / 128), dim3(256), 0, stream,
                     Ob, Wob, b_o, out, B_ * S_, HID_, HID_);
}

// Round 3
// 253.644 us; speedup vs baseline: 1.5255x; 1.5255x over previous
//
#include <hip/hip_runtime.h>
#include <hip/hip_bf16.h>
#include <stdint.h>

typedef __bf16 bf16x8 __attribute__((ext_vector_type(8)));
typedef float f32x4 __attribute__((ext_vector_type(4)));
typedef float f32x16 __attribute__((ext_vector_type(16)));
typedef float f32x4v __attribute__((ext_vector_type(4)));
typedef unsigned short u16;
typedef unsigned int u32;
typedef u16 u16x8 __attribute__((ext_vector_type(8)));
typedef u32 u32x4 __attribute__((ext_vector_type(4)));

#define B_ 2
#define S_ 2048
#define HID_ 2048
#define H_ 16
#define HK_ 4
#define D_ 128
#define NQKV_ 3072

__device__ __forceinline__ u16 f2bf(float f) {
  u32 u = __builtin_bit_cast(u32, f);
  u32 r = (u + 0x7fffu + ((u >> 16) & 1u)) >> 16;
  return (u16)r;
}

__device__ __forceinline__ u32 cvtpk(float lo, float hi) {
  u32 r;
  asm("v_cvt_pk_bf16_f32 %0, %1, %2" : "=v"(r) : "v"(lo), "v"(hi));
  return r;
}

__device__ __forceinline__ void gload_lds16(const void* g, void* l) {
  __builtin_amdgcn_global_load_lds((const __attribute__((address_space(1))) void*)g,
                                   (__attribute__((address_space(3))) void*)l, 16, 0, 0);
}

// ---------------- f32 -> bf16 bulk convert ----------------
__global__ __launch_bounds__(256) void k_f32_to_bf16(const float* __restrict__ in,
                                                     u16* __restrict__ out, int n8) {
  for (int i = blockIdx.x * 256 + threadIdx.x; i < n8; i += gridDim.x * 256) {
    const f32x4v* p = (const f32x4v*)(in + (size_t)i * 8);
    f32x4v a = p[0], b = p[1];
    u16x8 w;
    w[0] = f2bf(a[0]); w[1] = f2bf(a[1]); w[2] = f2bf(a[2]); w[3] = f2bf(a[3]);
    w[4] = f2bf(b[0]); w[5] = f2bf(b[1]); w[6] = f2bf(b[2]); w[7] = f2bf(b[3]);
    *(u16x8*)(out + (size_t)i * 8) = w;
  }
}

// ---------------- bf16 GEMM: C[M][N] = A[M][K] * B[N][K]^T + bias ----------------
__global__ __launch_bounds__(256) void k_gemm_bt(const u16* __restrict__ A, const u16* __restrict__ Bm,
                                                 const float* __restrict__ bias, float* __restrict__ C,
                                                 int M, int N, int K) {
  __shared__ __attribute__((aligned(16))) u16 lA[128 * 32];
  __shared__ __attribute__((aligned(16))) u16 lB[128 * 32];
  const int tid = threadIdx.x;
  const int lane = tid & 63, wid = tid >> 6;
  const int wr = wid >> 1, wc = wid & 1;
  const int row0 = blockIdx.y * 128, col0 = blockIdx.x * 128;
  const int l15 = lane & 15, l4 = lane >> 4;
  f32x4 acc[4][4] = {};

  for (int k0 = 0; k0 < K; k0 += 32) {
#pragma unroll
    for (int iss = 0; iss < 2; ++iss) {
      int ob_w = wid * 2048 + iss * 1024;
      int ob = ob_w + lane * 16;
      int r = ob >> 6, cb = ob & 63;
      gload_lds16((const char*)A + ((size_t)(row0 + r) * K + k0) * 2 + cb, (char*)lA + ob_w);
      gload_lds16((const char*)Bm + ((size_t)(col0 + r) * K + k0) * 2 + cb, (char*)lB + ob_w);
    }
    __syncthreads();
    bf16x8 af[4], bf[4];
#pragma unroll
    for (int m = 0; m < 4; ++m) af[m] = *(const bf16x8*)&lA[(wr * 64 + m * 16 + l15) * 32 + l4 * 8];
#pragma unroll
    for (int n = 0; n < 4; ++n) bf[n] = *(const bf16x8*)&lB[(wc * 64 + n * 16 + l15) * 32 + l4 * 8];
#pragma unroll
    for (int m = 0; m < 4; ++m)
#pragma unroll
      for (int n = 0; n < 4; ++n)
        acc[m][n] = __builtin_amdgcn_mfma_f32_16x16x32_bf16(af[m], bf[n], acc[m][n], 0, 0, 0);
    __syncthreads();
  }
#pragma unroll
  for (int m = 0; m < 4; ++m) {
    int grow_b = row0 + wr * 64 + m * 16 + l4 * 4;
#pragma unroll
    for (int n = 0; n < 4; ++n) {
      int gcol = col0 + wc * 64 + n * 16 + l15;
      float bv = bias[gcol];
#pragma unroll
      for (int r2 = 0; r2 < 4; ++r2)
        C[(size_t)(grow_b + r2) * N + gcol] = acc[m][n][r2] + bv;
    }
  }
}

// ---------------- RoPE + split + layout ----------------
__global__ __launch_bounds__(256) void k_rope_split(const float* __restrict__ qkv,
                                                    const float* __restrict__ cosb,
                                                    const float* __restrict__ sinb,
                                                    u16* __restrict__ Qb, u16* __restrict__ Kb,
                                                    u16* __restrict__ Vt) {
  const int bs = blockIdx.x;
  const int b = bs >> 11, s = bs & 2047;
  const size_t base = (size_t)bs * NQKV_;
  const size_t cs = (size_t)bs * D_;
  const float qscale = 0.08838834764831845f;  // 1/sqrt(128)
  for (int p = threadIdx.x; p < H_ * 64; p += 256) {
    int h = p >> 6, d = p & 63;
    float f1 = qkv[base + h * D_ + d];
    float f2 = qkv[base + h * D_ + 64 + d];
    float c1 = cosb[cs + d], s1 = sinb[cs + d];
    float c2 = cosb[cs + 64 + d], s2 = sinb[cs + 64 + d];
    size_t o = ((size_t)(b * H_ + h) * S_ + s) * D_ + d;
    Qb[o] = f2bf((f1 * c1 - f2 * s1) * qscale);
    Qb[o + 64] = f2bf((f2 * c2 + f1 * s2) * qscale);
  }
  for (int p = threadIdx.x; p < HK_ * 64; p += 256) {
    int hk = p >> 6, d = p & 63;
    float f1 = qkv[base + H_ * D_ + hk * D_ + d];
    float f2 = qkv[base + H_ * D_ + hk * D_ + 64 + d];
    float c1 = cosb[cs + d], s1 = sinb[cs + d];
    float c2 = cosb[cs + 64 + d], s2 = sinb[cs + 64 + d];
    size_t o = ((size_t)(b * HK_ + hk) * S_ + s) * D_ + d;
    Kb[o] = f2bf(f1 * c1 - f2 * s1);
    Kb[o + 64] = f2bf(f2 * c2 + f1 * s2);
  }
  for (int p = threadIdx.x; p < HK_ * D_; p += 256) {
    int hk = p >> 7, d = p & 127;
    float v = qkv[base + H_ * D_ + HK_ * D_ + hk * D_ + d];
    Vt[((size_t)(b * HK_ + hk) * D_ + d) * S_ + s] = f2bf(v);
  }
}

// ---------------- flash attention: m214-style 8 waves x 32 q-rows, 32x32 MFMA,
//                  swapped QK^T, in-register softmax, O^T = V^T . P^T ----------------
__global__ __launch_bounds__(512, 2) void k_attn(const u16* __restrict__ Qb, const u16* __restrict__ Kb,
                                                 const u16* __restrict__ Vt, u16* __restrict__ Ob) {
  __shared__ __attribute__((aligned(16))) char lds[65536];
  char* lKc = lds;            // K tile [64 key][128 d] bf16, XOR (row&15)<<4
  char* lVc = lds + 16384;    // V^T tile [128 d][64 key] bf16, XOR (row&7)<<4
  const int qt = blockIdx.x;  // 0..7
  const int bh = blockIdx.y;  // 0..31
  const int b = bh >> 4, h = bh & 15, hk = h >> 2;
  const int tid = threadIdx.x, lane = tid & 63, wid = tid >> 6;
  const int l31 = lane & 31, hi = lane >> 5;

  // Q B-frags: lane holds Q[q = l31][d = ks*16 + hi*8 + j]
  const int qrow = qt * 256 + wid * 32 + l31;
  const u16* qptr = Qb + ((size_t)(b * H_ + h) * S_ + qrow) * D_;
  bf16x8 qf[8];
#pragma unroll
  for (int ks = 0; ks < 8; ++ks) qf[ks] = *(const bf16x8*)(qptr + ks * 16 + hi * 8);

  const u16* kbase = Kb + (size_t)(b * HK_ + hk) * S_ * D_;
  const u16* vbase = Vt + (size_t)(b * HK_ + hk) * D_ * S_;

  // staging: 512 threads x 2 slots of 16B each for K (16KB) and V^T (16KB)
  int krow[2], kc[2], vrow[2], vc[2];
#pragma unroll
  for (int i = 0; i < 2; ++i) {
    int s = tid + i * 512;
    krow[i] = s >> 4; kc[i] = s & 15;
    vrow[i] = s >> 3; vc[i] = s & 7;
  }

  f32x16 o[4] = {};
  float mrun = -1e30f, lrun = 0.f;

  bf16x8 kreg[2], vreg[2];
#pragma unroll
  for (int i = 0; i < 2; ++i) {
    kreg[i] = *(const bf16x8*)(kbase + (size_t)krow[i] * D_ + kc[i] * 8);
    vreg[i] = *(const bf16x8*)(vbase + (size_t)vrow[i] * S_ + vc[i] * 8);
  }
#pragma unroll
  for (int i = 0; i < 2; ++i) {
    *(bf16x8*)(lKc + ((krow[i] * 256 + kc[i] * 16) ^ ((krow[i] & 15) << 4))) = kreg[i];
    *(bf16x8*)(lVc + ((vrow[i] * 128 + vc[i] * 16) ^ ((vrow[i] & 7) << 4))) = vreg[i];
  }
  __syncthreads();

  for (int kt = 0; kt < 32; ++kt) {
    // T14: issue next tile's global loads early; write to LDS after the barrier
    if (kt < 31) {
#pragma unroll
      for (int i = 0; i < 2; ++i) {
        kreg[i] = *(const bf16x8*)(kbase + (size_t)((kt + 1) * 64 + krow[i]) * D_ + kc[i] * 8);
        vreg[i] = *(const bf16x8*)(vbase + (size_t)vrow[i] * S_ + (kt + 1) * 64 + vc[i] * 8);
      }
    }

    // swapped QK^T: sc[T] = S^T tile, rows k = 32T + (r&3)+8*(r>>2)+4hi, col q = l31
    f32x16 sc[2] = {};
    __builtin_amdgcn_s_setprio(1);
#pragma unroll
    for (int ks = 0; ks < 8; ++ks) {
#pragma unroll
      for (int T = 0; T < 2; ++T) {
        int row = T * 32 + l31;
        bf16x8 kf = *(const bf16x8*)(lKc + ((row * 256 + ks * 32 + hi * 16) ^ ((row & 15) << 4)));
        sc[T] = __builtin_amdgcn_mfma_f32_32x32x16_bf16(kf, qf[ks], sc[T], 0, 0, 0);
      }
    }
    __builtin_amdgcn_s_setprio(0);

    // in-register online softmax (one q per lane; hi halves hold disjoint k)
    float pmax = sc[0][0];
#pragma unroll
    for (int r = 1; r < 16; ++r) pmax = fmaxf(pmax, sc[0][r]);
#pragma unroll
    for (int r = 0; r < 16; ++r) pmax = fmaxf(pmax, sc[1][r]);
    pmax = fmaxf(pmax, __shfl_xor(pmax, 32));
    if (__any(pmax > mrun + 8.f)) {   // T13 defer-max
      float mn = fmaxf(mrun, pmax);
      float alpha = __expf(mrun - mn);
      mrun = mn;
      lrun *= alpha;
#pragma unroll
      for (int dt = 0; dt < 4; ++dt)
#pragma unroll
        for (int r = 0; r < 16; ++r) o[dt][r] *= alpha;
    }
    float rs = 0.f;
#pragma unroll
    for (int T = 0; T < 2; ++T)
#pragma unroll
      for (int r = 0; r < 16; ++r) {
        float p = __expf(sc[T][r] - mrun);
        sc[T][r] = p;
        rs += p;
      }
    rs += __shfl_xor(rs, 32);
    lrun += rs;

    // T12 (safe form): pack P^T into B-frags. kstep ks2 = 2T+g covers k-local 32T+16g..+16
    bf16x8 pf[4];
#pragma unroll
    for (int T = 0; T < 2; ++T) {
#pragma unroll
      for (int g = 0; g < 2; ++g) {
        u32 a0 = cvtpk(sc[T][8 * g + 0], sc[T][8 * g + 1]);
        u32 a1 = cvtpk(sc[T][8 * g + 2], sc[T][8 * g + 3]);
        u32 a2 = cvtpk(sc[T][8 * g + 4], sc[T][8 * g + 5]);
        u32 a3 = cvtpk(sc[T][8 * g + 6], sc[T][8 * g + 7]);
        u32 x0 = (u32)__shfl_xor((int)a0, 32);
        u32 x1 = (u32)__shfl_xor((int)a1, 32);
        u32 x2 = (u32)__shfl_xor((int)a2, 32);
        u32 x3 = (u32)__shfl_xor((int)a3, 32);
        u32 s0 = hi ? x2 : a0;   // k' = base+{0,1}
        u32 s1 = hi ? x3 : a1;   // k' = base+{2,3}
        u32 s2 = hi ? a2 : x0;   // k' = base+{4,5}
        u32 s3 = hi ? a3 : x1;   // k' = base+{6,7}
        u32x4 w = {s0, s1, s2, s3};
        pf[T * 2 + g] = __builtin_bit_cast(bf16x8, w);
      }
    }

    // PV: O^T[dt] += V^T-frag(32d x 16k) . P^T-frag(16k x 32q)
    __builtin_amdgcn_s_setprio(1);
#pragma unroll
    for (int ks2 = 0; ks2 < 4; ++ks2) {
#pragma unroll
      for (int dt = 0; dt < 4; ++dt) {
        int row = dt * 32 + l31;
        bf16x8 vf = *(const bf16x8*)(lVc + ((row * 128 + ks2 * 32 + hi * 16) ^ ((row & 7) << 4)));
        o[dt] = __builtin_amdgcn_mfma_f32_32x32x16_bf16(vf, pf[ks2], o[dt], 0, 0, 0);
      }
    }
    __builtin_amdgcn_s_setprio(0);

    __syncthreads();
    if (kt < 31) {
#pragma unroll
      for (int i = 0; i < 2; ++i) {
        *(bf16x8*)(lKc + ((krow[i] * 256 + kc[i] * 16) ^ ((krow[i] & 15) << 4))) = kreg[i];
        *(bf16x8*)(lVc + ((vrow[i] * 128 + vc[i] * 16) ^ ((vrow[i] & 7) << 4))) = vreg[i];
      }
    }
    __syncthreads();
  }

  // epilogue: O^T -> O via per-wave LDS region (8KB each), then coalesced stores
  float inv = 1.0f / lrun;
  char* myreg = lds + wid * 8192;  // [32 q][128 d] bf16, XOR (q&15)<<4 on byte-in-row
#pragma unroll
  for (int dt = 0; dt < 4; ++dt)
#pragma unroll
    for (int t = 0; t < 8; ++t) {
      u32 w = cvtpk(o[dt][2 * t] * inv, o[dt][2 * t + 1] * inv);
      int d0 = dt * 32 + 2 * (t & 1) + 8 * (t >> 1) + 4 * hi;
      *(u32*)(myreg + ((l31 * 256 + d0 * 2) ^ ((l31 & 15) << 4))) = w;
    }
  asm volatile("s_waitcnt lgkmcnt(0)");
  {
    int q = lane >> 1, hf = lane & 1;
    int srow = qt * 256 + wid * 32 + q;
    u16* orow = Ob + ((size_t)(b * S_ + srow)) * HID_ + h * 128 + hf * 64;
#pragma unroll
    for (int i = 0; i < 8; ++i) {
      bf16x8 vv = *(const bf16x8*)(myreg + ((q * 256 + hf * 128 + i * 16) ^ ((q & 15) << 4)));
      *(bf16x8*)(orow + i * 8) = vv;
    }
  }
}

extern "C" void kernel_launch(void* const* d_in, const int* in_sizes, int n_in,
                              void* d_out, int out_size, void* d_ws, size_t ws_size,
                              hipStream_t stream) {
  const float* hs = (const float*)d_in[0];
  const float* cosb = (const float*)d_in[1];
  const float* sinb = (const float*)d_in[2];
  const float* w_qkv = (const float*)d_in[3];
  const float* b_qkv = (const float*)d_in[4];
  const float* w_o = (const float*)d_in[5];
  const float* b_o = (const float*)d_in[6];
  float* out = (float*)d_out;

  char* ws = (char*)d_ws;
  u16* Xb    = (u16*)ws;                          // 16,777,216 B (reused as attn_out)
  u16* Wqkvb = (u16*)(ws + 16777216);             // 12,582,912 B
  u16* Wob   = (u16*)(ws + 29360128);             //  8,388,608 B
  float* qkv = (float*)(ws + 37748736);           // 50,331,648 B
  u16* Qb    = (u16*)(ws + 88080384);             // 16,777,216 B
  u16* Kb    = (u16*)(ws + 104857600);            //  4,194,304 B
  u16* Vt    = (u16*)(ws + 109051904);            //  4,194,304 B  (total 113,246,208 B)
  u16* Ob = Xb;

  hipLaunchKernelGGL(k_f32_to_bf16, dim3(2048), dim3(256), 0, stream, hs, Xb, (B_ * S_ * HID_) / 8);
  hipLaunchKernelGGL(k_f32_to_bf16, dim3(1536), dim3(256), 0, stream, w_qkv, Wqkvb, (NQKV_ * HID_) / 8);
  hipLaunchKernelGGL(k_f32_to_bf16, dim3(1024), dim3(256), 0, stream, w_o, Wob, (HID_ * HID_) / 8);
  hipLaunchKernelGGL(k_gemm_bt, dim3(NQKV_ / 128, (B_ * S_) / 128), dim3(256), 0, stream,
                     Xb, Wqkvb, b_qkv, qkv, B_ * S_, NQKV_, HID_);
  hipLaunchKernelGGL(k_rope_split, dim3(B_ * S_), dim3(256), 0, stream, qkv, cosb, sinb, Qb, Kb, Vt);
  hipLaunchKernelGGL(k_attn, dim3(S_ / 256, B_ * H_), dim3(512), 0, stream, Qb, Kb, Vt, Ob);
  hipLaunchKernelGGL(k_gemm_bt, dim3(HID_ / 128, (B_ * S_) / 128), dim3(256), 0, stream,
                     Ob, Wob, b_o, out, B_ * S_, HID_, HID_);
}

// Round 4
// 222.033 us; speedup vs baseline: 1.7427x; 1.1424x over previous
//
#include <hip/hip_runtime.h>
#include <hip/hip_bf16.h>
#include <stdint.h>

typedef __bf16 bf16x8 __attribute__((ext_vector_type(8)));
typedef float f32x4 __attribute__((ext_vector_type(4)));
typedef float f32x16 __attribute__((ext_vector_type(16)));
typedef float f32x4v __attribute__((ext_vector_type(4)));
typedef unsigned short u16;
typedef unsigned int u32;
typedef u16 u16x8 __attribute__((ext_vector_type(8)));
typedef u32 u32x4 __attribute__((ext_vector_type(4)));

#define B_ 2
#define S_ 2048
#define HID_ 2048
#define H_ 16
#define HK_ 4
#define D_ 128
#define NQKV_ 3072

__device__ __forceinline__ u16 f2bf(float f) {
  u32 u = __builtin_bit_cast(u32, f);
  u32 r = (u + 0x7fffu + ((u >> 16) & 1u)) >> 16;
  return (u16)r;
}
__device__ __forceinline__ float bf2f(u16 v) {
  u32 u = ((u32)v) << 16;
  return __builtin_bit_cast(float, u);
}
__device__ __forceinline__ u32 cvtpk(float lo, float hi) {
  u32 r;
  asm("v_cvt_pk_bf16_f32 %0, %1, %2" : "=v"(r) : "v"(lo), "v"(hi));
  return r;
}
__device__ __forceinline__ void gload_lds16(const void* g, void* l) {
  __builtin_amdgcn_global_load_lds((const __attribute__((address_space(1))) void*)g,
                                   (__attribute__((address_space(3))) void*)l, 16, 0, 0);
}

// ---------------- f32 -> bf16 bulk convert ----------------
__global__ __launch_bounds__(256) void k_f32_to_bf16(const float* __restrict__ in,
                                                     u16* __restrict__ out, int n8) {
  for (int i = blockIdx.x * 256 + threadIdx.x; i < n8; i += gridDim.x * 256) {
    const f32x4v* p = (const f32x4v*)(in + (size_t)i * 8);
    f32x4v a = p[0], b = p[1];
    u16x8 w;
    w[0] = f2bf(a[0]); w[1] = f2bf(a[1]); w[2] = f2bf(a[2]); w[3] = f2bf(a[3]);
    w[4] = f2bf(b[0]); w[5] = f2bf(b[1]); w[6] = f2bf(b[2]); w[7] = f2bf(b[3]);
    *(u16x8*)(out + (size_t)i * 8) = w;
  }
}

// ---------------- 8-phase deep-pipelined GEMM: C = A[M][K] . B[N][K]^T + bias ----
// BN=256 fixed; BM in {256,128}. 8 waves (2M x 4N), BK=64, 2 LDS dbufs, counted vmcnt.
// Swizzle byte^=((row&7)<<4): linear gload_lds dest + inverse-swizzled global source.
template <int ISSUES>
__device__ __forceinline__ void stage_half(const u16* __restrict__ src, int K, char* ldsb, int tid) {
#pragma unroll
  for (int i = 0; i < ISSUES; ++i) {
    int off = i * 8192 + tid * 16;
    int r = off >> 7, cb = off & 127;
    int scb = cb ^ ((r & 7) << 4);
    gload_lds16((const char*)(src + (size_t)r * K) + scb, ldsb + i * 8192 + (tid & ~63) * 16);
  }
}

template <int BM, typename CT>
__global__ __launch_bounds__(512, 1) void k_gemm8p(const u16* __restrict__ A, const u16* __restrict__ Bm,
                                                   const float* __restrict__ bias, CT* __restrict__ C,
                                                   int M, int N, int K) {
  constexpr int HAR = BM / 2;            // rows per A half-tile
  constexpr int AHB = HAR * 128;         // bytes per A half-tile
  constexpr int AISS = AHB / 8192;       // gload issues per A half
  constexpr int MREP = BM / 32;          // 16-row frags per wave
  constexpr int MQ = MREP / 4;           // m-frags per phase
  constexpr int DB = 2 * AHB + 32768;    // dbuf stride
  __shared__ __attribute__((aligned(16))) char lds[2 * DB];
  const int tid = threadIdx.x, lane = tid & 63;
  const int wid = tid >> 6, wm = wid >> 2, wn = wid & 3;
  const int l15 = lane & 15, l4 = lane >> 4;
  const int row0 = blockIdx.y * BM, col0 = blockIdx.x * 256;
  const int NT = K >> 6;

  f32x4 acc[MREP][4] = {};

  auto stageA = [&](int t, int h) {
    stage_half<AISS>(A + (size_t)(row0 + h * HAR) * K + t * 64, K, lds + (t & 1) * DB + h * AHB, tid);
  };
  auto stageB = [&](int t, int h) {
    stage_half<2>(Bm + (size_t)(col0 + h * 128) * K + t * 64, K, lds + (t & 1) * DB + 2 * AHB + h * 16384, tid);
  };

  // prologue: tile0 fully + tile1 B halves; force tile0 (leave B(1) pair in flight)
  stageA(0, 0); stageA(0, 1); stageB(0, 0); stageB(0, 1);
  if (NT > 1) { stageB(1, 0); stageB(1, 1); }
  if (NT > 1) asm volatile("s_waitcnt vmcnt(4)" ::: "memory");
  else        asm volatile("s_waitcnt vmcnt(0)" ::: "memory");
  __builtin_amdgcn_s_barrier();

  const char* myA = lds + wm * AHB;
  const char* myB = lds + 2 * AHB + (wn >> 1) * 16384;
  const int rBb = (wn & 1) * 64;

  for (int t = 0; t < NT; ++t) {
    const int d = t & 1;
    const char* Ab = myA + d * DB;
    const char* Bb = myB + d * DB;
    bf16x8 bfr[4][2];
#pragma unroll
    for (int j = 0; j < 4; ++j) {
      if (j == 0) {
#pragma unroll
        for (int n = 0; n < 4; ++n)
#pragma unroll
          for (int ks = 0; ks < 2; ++ks) {
            int r = rBb + n * 16 + l15;
            bfr[n][ks] = *(const bf16x8*)(Bb + r * 128 + ((ks * 64 + l4 * 16) ^ ((r & 7) << 4)));
          }
      }
      bf16x8 afr[MQ][2];
#pragma unroll
      for (int mq = 0; mq < MQ; ++mq)
#pragma unroll
        for (int ks = 0; ks < 2; ++ks) {
          int r = (j * MQ + mq) * 16 + l15;
          afr[mq][ks] = *(const bf16x8*)(Ab + r * 128 + ((ks * 64 + l4 * 16) ^ ((r & 7) << 4)));
        }
      // stage slot (ledger: p0/p1 -> A(t+1); p2/p3 -> B(t+2); drain at p3)
      if (j == 0) { if (t + 1 < NT) stageA(t + 1, 0); }
      else if (j == 1) { if (t + 1 < NT) stageA(t + 1, 1); }
      else if (j == 2) { if (t + 2 < NT) stageB(t + 2, 0); }
      else {
        if (t + 2 < NT) { stageB(t + 2, 1); asm volatile("s_waitcnt vmcnt(4)" ::: "memory"); }
        else             asm volatile("s_waitcnt vmcnt(0)" ::: "memory");
      }
      __builtin_amdgcn_s_barrier();
      asm volatile("s_waitcnt lgkmcnt(0)" ::: "memory");
      __builtin_amdgcn_s_setprio(1);
#pragma unroll
      for (int mq = 0; mq < MQ; ++mq)
#pragma unroll
        for (int ks = 0; ks < 2; ++ks)
#pragma unroll
          for (int n = 0; n < 4; ++n)
            acc[j * MQ + mq][n] =
                __builtin_amdgcn_mfma_f32_16x16x32_bf16(afr[mq][ks], bfr[n][ks], acc[j * MQ + mq][n], 0, 0, 0);
      __builtin_amdgcn_s_setprio(0);
      __builtin_amdgcn_s_barrier();
    }
  }

  // epilogue
#pragma unroll
  for (int m = 0; m < MREP; ++m) {
    int grow = row0 + wm * HAR + m * 16 + l4 * 4;
#pragma unroll
    for (int n = 0; n < 4; ++n) {
      int gcol = col0 + wn * 64 + n * 16 + l15;
      float bv = bias[gcol];
#pragma unroll
      for (int r2 = 0; r2 < 4; ++r2) {
        float v = acc[m][n][r2] + bv;
        if constexpr (sizeof(CT) == 2) C[(size_t)(grow + r2) * N + gcol] = (CT)f2bf(v);
        else                           C[(size_t)(grow + r2) * N + gcol] = v;
      }
    }
  }
}

// ---------------- RoPE + split + layout (qkv now bf16) ----------------
__global__ __launch_bounds__(256) void k_rope_split(const u16* __restrict__ qkv,
                                                    const float* __restrict__ cosb,
                                                    const float* __restrict__ sinb,
                                                    u16* __restrict__ Qb, u16* __restrict__ Kb,
                                                    u16* __restrict__ Vt) {
  const int bs = blockIdx.x;
  const int b = bs >> 11, s = bs & 2047;
  const size_t base = (size_t)bs * NQKV_;
  const size_t cs = (size_t)bs * D_;
  const float qscale = 0.08838834764831845f;  // 1/sqrt(128)
  for (int p = threadIdx.x; p < H_ * 64; p += 256) {
    int h = p >> 6, d = p & 63;
    float f1 = bf2f(qkv[base + h * D_ + d]);
    float f2 = bf2f(qkv[base + h * D_ + 64 + d]);
    float c1 = cosb[cs + d], s1 = sinb[cs + d];
    float c2 = cosb[cs + 64 + d], s2 = sinb[cs + 64 + d];
    size_t o = ((size_t)(b * H_ + h) * S_ + s) * D_ + d;
    Qb[o] = f2bf((f1 * c1 - f2 * s1) * qscale);
    Qb[o + 64] = f2bf((f2 * c2 + f1 * s2) * qscale);
  }
  for (int p = threadIdx.x; p < HK_ * 64; p += 256) {
    int hk = p >> 6, d = p & 63;
    float f1 = bf2f(qkv[base + H_ * D_ + hk * D_ + d]);
    float f2 = bf2f(qkv[base + H_ * D_ + hk * D_ + 64 + d]);
    float c1 = cosb[cs + d], s1 = sinb[cs + d];
    float c2 = cosb[cs + 64 + d], s2 = sinb[cs + 64 + d];
    size_t o = ((size_t)(b * HK_ + hk) * S_ + s) * D_ + d;
    Kb[o] = f2bf(f1 * c1 - f2 * s1);
    Kb[o + 64] = f2bf(f2 * c2 + f1 * s2);
  }
  for (int p = threadIdx.x; p < HK_ * D_; p += 256) {
    int hk = p >> 7, d = p & 127;
    Vt[((size_t)(b * HK_ + hk) * D_ + d) * S_ + s] = qkv[base + H_ * D_ + HK_ * D_ + hk * D_ + d];
  }
}

// ---------------- flash attention: 8 waves x 32 q-rows, 32x32 MFMA,
//                  swapped QK^T, in-register softmax, O^T = V^T . P^T ----------------
__global__ __launch_bounds__(512, 2) void k_attn(const u16* __restrict__ Qb, const u16* __restrict__ Kb,
                                                 const u16* __restrict__ Vt, u16* __restrict__ Ob) {
  __shared__ __attribute__((aligned(16))) char lds[65536];
  char* lKc = lds;            // K tile [64 key][128 d] bf16, XOR (row&15)<<4
  char* lVc = lds + 16384;    // V^T tile [128 d][64 key] bf16, XOR (row&7)<<4
  const int qt = blockIdx.x;  // 0..7
  const int bh = blockIdx.y;  // 0..31
  const int b = bh >> 4, h = bh & 15, hk = h >> 2;
  const int tid = threadIdx.x, lane = tid & 63, wid = tid >> 6;
  const int l31 = lane & 31, hi = lane >> 5;

  const int qrow = qt * 256 + wid * 32 + l31;
  const u16* qptr = Qb + ((size_t)(b * H_ + h) * S_ + qrow) * D_;
  bf16x8 qf[8];
#pragma unroll
  for (int ks = 0; ks < 8; ++ks) qf[ks] = *(const bf16x8*)(qptr + ks * 16 + hi * 8);

  const u16* kbase = Kb + (size_t)(b * HK_ + hk) * S_ * D_;
  const u16* vbase = Vt + (size_t)(b * HK_ + hk) * D_ * S_;

  int krow[2], kc[2], vrow[2], vc[2];
#pragma unroll
  for (int i = 0; i < 2; ++i) {
    int s = tid + i * 512;
    krow[i] = s >> 4; kc[i] = s & 15;
    vrow[i] = s >> 3; vc[i] = s & 7;
  }

  f32x16 o[4] = {};
  float mrun = -1e30f, lrun = 0.f;

  bf16x8 kreg[2], vreg[2];
#pragma unroll
  for (int i = 0; i < 2; ++i) {
    kreg[i] = *(const bf16x8*)(kbase + (size_t)krow[i] * D_ + kc[i] * 8);
    vreg[i] = *(const bf16x8*)(vbase + (size_t)vrow[i] * S_ + vc[i] * 8);
  }
#pragma unroll
  for (int i = 0; i < 2; ++i) {
    *(bf16x8*)(lKc + ((krow[i] * 256 + kc[i] * 16) ^ ((krow[i] & 15) << 4))) = kreg[i];
    *(bf16x8*)(lVc + ((vrow[i] * 128 + vc[i] * 16) ^ ((vrow[i] & 7) << 4))) = vreg[i];
  }
  __syncthreads();

  for (int kt = 0; kt < 32; ++kt) {
    if (kt < 31) {
#pragma unroll
      for (int i = 0; i < 2; ++i) {
        kreg[i] = *(const bf16x8*)(kbase + (size_t)((kt + 1) * 64 + krow[i]) * D_ + kc[i] * 8);
        vreg[i] = *(const bf16x8*)(vbase + (size_t)vrow[i] * S_ + (kt + 1) * 64 + vc[i] * 8);
      }
    }

    f32x16 sc[2] = {};
    __builtin_amdgcn_s_setprio(1);
#pragma unroll
    for (int ks = 0; ks < 8; ++ks) {
#pragma unroll
      for (int T = 0; T < 2; ++T) {
        int row = T * 32 + l31;
        bf16x8 kf = *(const bf16x8*)(lKc + ((row * 256 + ks * 32 + hi * 16) ^ ((row & 15) << 4)));
        sc[T] = __builtin_amdgcn_mfma_f32_32x32x16_bf16(kf, qf[ks], sc[T], 0, 0, 0);
      }
    }
    __builtin_amdgcn_s_setprio(0);

    float pmax = sc[0][0];
#pragma unroll
    for (int r = 1; r < 16; ++r) pmax = fmaxf(pmax, sc[0][r]);
#pragma unroll
    for (int r = 0; r < 16; ++r) pmax = fmaxf(pmax, sc[1][r]);
    pmax = fmaxf(pmax, __shfl_xor(pmax, 32));
    if (__any(pmax > mrun + 8.f)) {
      float mn = fmaxf(mrun, pmax);
      float alpha = __expf(mrun - mn);
      mrun = mn;
      lrun *= alpha;
#pragma unroll
      for (int dt = 0; dt < 4; ++dt)
#pragma unroll
        for (int r = 0; r < 16; ++r) o[dt][r] *= alpha;
    }
    float rs = 0.f;
#pragma unroll
    for (int T = 0; T < 2; ++T)
#pragma unroll
      for (int r = 0; r < 16; ++r) {
        float p = __expf(sc[T][r] - mrun);
        sc[T][r] = p;
        rs += p;
      }
    rs += __shfl_xor(rs, 32);
    lrun += rs;

    bf16x8 pf[4];
#pragma unroll
    for (int T = 0; T < 2; ++T) {
#pragma unroll
      for (int g = 0; g < 2; ++g) {
        u32 a0 = cvtpk(sc[T][8 * g + 0], sc[T][8 * g + 1]);
        u32 a1 = cvtpk(sc[T][8 * g + 2], sc[T][8 * g + 3]);
        u32 a2 = cvtpk(sc[T][8 * g + 4], sc[T][8 * g + 5]);
        u32 a3 = cvtpk(sc[T][8 * g + 6], sc[T][8 * g + 7]);
        u32 x0 = (u32)__shfl_xor((int)a0, 32);
        u32 x1 = (u32)__shfl_xor((int)a1, 32);
        u32 x2 = (u32)__shfl_xor((int)a2, 32);
        u32 x3 = (u32)__shfl_xor((int)a3, 32);
        u32 s0 = hi ? x2 : a0;
        u32 s1 = hi ? x3 : a1;
        u32 s2 = hi ? a2 : x0;
        u32 s3 = hi ? a3 : x1;
        u32x4 w = {s0, s1, s2, s3};
        pf[T * 2 + g] = __builtin_bit_cast(bf16x8, w);
      }
    }

    __builtin_amdgcn_s_setprio(1);
#pragma unroll
    for (int ks2 = 0; ks2 < 4; ++ks2) {
#pragma unroll
      for (int dt = 0; dt < 4; ++dt) {
        int row = dt * 32 + l31;
        bf16x8 vf = *(const bf16x8*)(lVc + ((row * 128 + ks2 * 32 + hi * 16) ^ ((row & 7) << 4)));
        o[dt] = __builtin_amdgcn_mfma_f32_32x32x16_bf16(vf, pf[ks2], o[dt], 0, 0, 0);
      }
    }
    __builtin_amdgcn_s_setprio(0);

    __syncthreads();
    if (kt < 31) {
#pragma unroll
      for (int i = 0; i < 2; ++i) {
        *(bf16x8*)(lKc + ((krow[i] * 256 + kc[i] * 16) ^ ((krow[i] & 15) << 4))) = kreg[i];
        *(bf16x8*)(lVc + ((vrow[i] * 128 + vc[i] * 16) ^ ((vrow[i] & 7) << 4))) = vreg[i];
      }
    }
    __syncthreads();
  }

  float inv = 1.0f / lrun;
  char* myreg = lds + wid * 8192;
#pragma unroll
  for (int dt = 0; dt < 4; ++dt)
#pragma unroll
    for (int t = 0; t < 8; ++t) {
      u32 w = cvtpk(o[dt][2 * t] * inv, o[dt][2 * t + 1] * inv);
      int d0 = dt * 32 + 2 * (t & 1) + 8 * (t >> 1) + 4 * hi;
      *(u32*)(myreg + ((l31 * 256 + d0 * 2) ^ ((l31 & 15) << 4))) = w;
    }
  asm volatile("s_waitcnt lgkmcnt(0)");
  {
    int q = lane >> 1, hf = lane & 1;
    int srow = qt * 256 + wid * 32 + q;
    u16* orow = Ob + ((size_t)(b * S_ + srow)) * HID_ + h * 128 + hf * 64;
#pragma unroll
    for (int i = 0; i < 8; ++i) {
      bf16x8 vv = *(const bf16x8*)(myreg + ((q * 256 + hf * 128 + i * 16) ^ ((q & 15) << 4)));
      *(bf16x8*)(orow + i * 8) = vv;
    }
  }
}

extern "C" void kernel_launch(void* const* d_in, const int* in_sizes, int n_in,
                              void* d_out, int out_size, void* d_ws, size_t ws_size,
                              hipStream_t stream) {
  const float* hs = (const float*)d_in[0];
  const float* cosb = (const float*)d_in[1];
  const float* sinb = (const float*)d_in[2];
  const float* w_qkv = (const float*)d_in[3];
  const float* b_qkv = (const float*)d_in[4];
  const float* w_o = (const float*)d_in[5];
  const float* b_o = (const float*)d_in[6];
  float* out = (float*)d_out;

  char* ws = (char*)d_ws;
  u16* Xb    = (u16*)ws;                          // 16,777,216 B (reused as attn_out)
  u16* Wqkvb = (u16*)(ws + 16777216);             // 12,582,912 B
  u16* Wob   = (u16*)(ws + 29360128);             //  8,388,608 B
  u16* qkvb  = (u16*)(ws + 37748736);             // 25,165,824 B (bf16 now)
  u16* Qb    = (u16*)(ws + 62914560);             // 16,777,216 B
  u16* Kb    = (u16*)(ws + 79691776);             //  4,194,304 B
  u16* Vt    = (u16*)(ws + 83886080);             //  4,194,304 B  (total 88,080,384 B)
  u16* Ob = Xb;

  hipLaunchKernelGGL(k_f32_to_bf16, dim3(2048), dim3(256), 0, stream, hs, Xb, (B_ * S_ * HID_) / 8);
  hipLaunchKernelGGL(k_f32_to_bf16, dim3(1536), dim3(256), 0, stream, w_qkv, Wqkvb, (NQKV_ * HID_) / 8);
  hipLaunchKernelGGL(k_f32_to_bf16, dim3(1024), dim3(256), 0, stream, w_o, Wob, (HID_ * HID_) / 8);
  hipLaunchKernelGGL((k_gemm8p<256, u16>), dim3(NQKV_ / 256, (B_ * S_) / 256), dim3(512), 0, stream,
                     Xb, Wqkvb, b_qkv, qkvb, B_ * S_, NQKV_, HID_);
  hipLaunchKernelGGL(k_rope_split, dim3(B_ * S_), dim3(256), 0, stream, qkvb, cosb, sinb, Qb, Kb, Vt);
  hipLaunchKernelGGL(k_attn, dim3(S_ / 256, B_ * H_), dim3(512), 0, stream, Qb, Kb, Vt, Ob);
  hipLaunchKernelGGL((k_gemm8p<128, float>), dim3(HID_ / 256, (B_ * S_) / 128), dim3(512), 0, stream,
                     Ob, Wob, b_o, out, B_ * S_, HID_, HID_);
}